// Round 4
// baseline (80.677 us; speedup 1.0000x reference)
//
#include <hip/hip_runtime.h>
#include <hip/hip_bf16.h>

#define B_DIM 32
#define T_DIM 2048
#define D_DIM 1024
#define S_MAXK 32
#define LSTRIDE 256   // max t-list length per (b,s); true max ~100 (binomial tail)

// ws layout (bytes):
//   h      float[B][32][D]      @ 0        : 4,194,304  (mean |x| per (b,step))
//   perm   int  [B][32][LSTRIDE]@ 4194304  : 1,048,576
//   counts uint [B][32]         @ 5242880  : 4,096
//   pos    uint [B][32]         @ 5246976  : 4,096
//   ordl   int  [B][32]         @ 5251072  : 4,096
//   E      float[B][31]         @ 5255168  : 3,968
#define H_OFF      0
#define PERM_OFF   4194304
#define COUNTS_OFF 5242880
#define POS_OFF    5246976
#define ORDL_OFF   5251072
#define E_OFF      5255168

// One block per b: ballot/popc counting sort of t by step, first-pos, counts,
// and the stable argsort of pos. No atomics anywhere.
__global__ __launch_bounds__(256) void k_prep(const int* __restrict__ sid,
                                              int* __restrict__ perm,
                                              unsigned* __restrict__ counts,
                                              unsigned* __restrict__ pos,
                                              int* __restrict__ ordl) {
    __shared__ int      sl[T_DIM];
    __shared__ unsigned posl[32];

    const int b = blockIdx.x;
    const int tid = threadIdx.x;
    for (int t = tid; t < T_DIM; t += 256) sl[t] = sid[b * T_DIM + t];
    __syncthreads();

    const int wave = tid >> 6;
    const int lane = tid & 63;
    const unsigned long long lt = (lane == 63) ? ~0ull >> 1 : (1ull << lane) - 1;

    for (int s8 = 0; s8 < 8; ++s8) {          // wave w owns steps w*8+1 .. w*8+8
        const int s = wave * 8 + s8 + 1;
        unsigned base = 0, first = T_DIM;
        for (int it = 0; it < T_DIM / 64; ++it) {
            int v = sl[it * 64 + lane];
            unsigned long long mask = __ballot(v == s);
            if (mask && first == (unsigned)T_DIM)
                first = (unsigned)(it * 64 + __ffsll((long long)mask) - 1);
            if (v == s) {
                unsigned idx = base + (unsigned)__popcll(mask & lt);
                if (idx < LSTRIDE)
                    perm[(((b << 5) + s - 1) << 8) + idx] = it * 64 + lane;
            }
            base += (unsigned)__popcll(mask);
        }
        if (lane == 0) {
            counts[(b << 5) + s - 1] = base;
            unsigned p = base ? first : (unsigned)T_DIM;
            posl[s - 1] = p;
            pos[(b << 5) + s - 1] = p;
        }
    }
    __syncthreads();

    if (tid < 32) {                           // stable argsort of pos
        unsigned ps = posl[tid];
        int r = 0;
        for (int j = 0; j < 32; ++j) {
            unsigned pj = posl[j];
            if (pj < ps || (pj == ps && j < tid)) r++;
        }
        ordl[(b << 5) + r] = tid;
    }
}

// One block per (b,step): pure gather of pre-listed rows, 8-deep batched
// float4 loads, mean written directly. No scan, no atomics.
__global__ __launch_bounds__(256) void k_gather(const float* __restrict__ x,
                                                const int* __restrict__ perm,
                                                const unsigned* __restrict__ counts,
                                                float* __restrict__ h) {
    __shared__ int list[LSTRIDE];
    const int b = blockIdx.x >> 5;
    const int s = blockIdx.x & 31;
    const int tid = threadIdx.x;

    const unsigned ntrue = counts[(b << 5) + s];
    const int n = (int)(ntrue < LSTRIDE ? ntrue : LSTRIDE);
    if (tid < n) list[tid] = perm[(((b << 5) + s) << 8) + tid];
    __syncthreads();

    const float4* xb = (const float4*)(x + (size_t)b * T_DIM * D_DIM);
    float4 acc = {0.f, 0.f, 0.f, 0.f};

    int i = 0;
    for (; i + 8 <= n; i += 8) {
        float4 v[8];
        #pragma unroll
        for (int j = 0; j < 8; ++j)
            v[j] = xb[(size_t)list[i + j] * (D_DIM / 4) + tid];
        #pragma unroll
        for (int j = 0; j < 8; ++j) {
            acc.x += fabsf(v[j].x); acc.y += fabsf(v[j].y);
            acc.z += fabsf(v[j].z); acc.w += fabsf(v[j].w);
        }
    }
    for (; i < n; ++i) {
        float4 v = xb[(size_t)list[i] * (D_DIM / 4) + tid];
        acc.x += fabsf(v.x); acc.y += fabsf(v.y);
        acc.z += fabsf(v.z); acc.w += fabsf(v.w);
    }

    const float r = 1.0f / (float)(ntrue > 1u ? ntrue : 1u);
    ((float4*)(h + (size_t)((b << 5) + s) * D_DIM))[tid] =
        make_float4(acc.x * r, acc.y * r, acc.z * r, acc.w * r);
}

// One block per (b, pair i): E[b][i] = mean_d relu(hA-hB)^2 (0 if pair invalid).
__global__ __launch_bounds__(256) void k_pairsE(const float* __restrict__ h,
                                                const int* __restrict__ ordl,
                                                const unsigned* __restrict__ pos,
                                                float* __restrict__ E) {
    const int b = blockIdx.x / 31;
    const int i = blockIdx.x % 31;
    const int tid = threadIdx.x;
    const int A  = ordl[(b << 5) + i];
    const int B2 = ordl[(b << 5) + i + 1];

    float e = 0.f;
    if (pos[(b << 5) + B2] < (unsigned)T_DIM) {    // pair_valid
        float4 a4 = ((const float4*)(h + (size_t)((b << 5) + A)  * D_DIM))[tid];
        float4 b4 = ((const float4*)(h + (size_t)((b << 5) + B2) * D_DIM))[tid];
        float d0 = fmaxf(a4.x - b4.x, 0.f);
        float d1 = fmaxf(a4.y - b4.y, 0.f);
        float d2 = fmaxf(a4.z - b4.z, 0.f);
        float d3 = fmaxf(a4.w - b4.w, 0.f);
        e = d0 * d0 + d1 * d1 + d2 * d2 + d3 * d3;
    }
    __shared__ float red[4];
    #pragma unroll
    for (int off = 32; off; off >>= 1) e += __shfl_down(e, off);
    if ((tid & 63) == 0) red[tid >> 6] = e;
    __syncthreads();
    if (tid == 0) E[b * 31 + i] = (red[0] + red[1] + red[2] + red[3]) * (1.f / D_DIM);
}

// Single block: per-b loss logic on 32 lanes, then reduce.
__global__ __launch_bounds__(256) void k_final(const float* __restrict__ E,
                                               const int* __restrict__ ordl,
                                               const unsigned* __restrict__ pos,
                                               const int* __restrict__ labels,
                                               float* __restrict__ out) {
    __shared__ float    El[B_DIM * 31];
    __shared__ int      ol[B_DIM * 32];
    __shared__ unsigned pl[B_DIM * 32];
    __shared__ float    partial[2];

    const int tid = threadIdx.x;
    for (int i = tid; i < B_DIM * 31; i += 256) El[i] = E[i];
    for (int i = tid; i < B_DIM * 32; i += 256) { ol[i] = ordl[i]; pl[i] = pos[i]; }
    __syncthreads();

    float contrib = 0.f, cf = 0.f;
    if (tid < 32) {
        const int b = tid;
        float lpos = 0.f, lneg = 0.f;
        int np = 0, ni = 0, n = 0;
        for (int s2 = 0; s2 < 32; ++s2) n += (pl[(b << 5) + s2] < T_DIM) ? 1 : 0;
        for (int i = 0; i < 31; ++i) {
            int A  = ol[(b << 5) + i];
            int B2 = ol[(b << 5) + i + 1];
            if (pl[(b << 5) + B2] < (unsigned)T_DIM) {
                float Ev = El[b * 31 + i];
                np++; lpos += Ev;
                if (A > B2) { ni++; lneg += fmaxf(1.0f - Ev, 0.0f); }  // ALPHA=1
            }
        }
        float loss_pos = lpos / (float)(np > 1 ? np : 1);
        float loss_neg = lneg / (float)(ni > 1 ? ni : 1);
        int lab = labels[b];
        bool pc = (lab == 1) && (n >= 2);
        bool nc = (lab == 0) && (ni > 0);
        contrib = (pc ? loss_pos : 0.0f) + (nc ? loss_neg : 0.0f);
        cf = (float)((pc ? 1 : 0) + (nc ? 1 : 0));
    }
    #pragma unroll
    for (int off = 16; off; off >>= 1) {
        contrib += __shfl_down(contrib, off);
        cf      += __shfl_down(cf, off);
    }
    if (tid == 0) { partial[0] = contrib; partial[1] = cf; }
    __syncthreads();
    if (tid == 0) out[0] = partial[0] / (partial[1] + 1e-9f);
}

extern "C" void kernel_launch(void* const* d_in, const int* in_sizes, int n_in,
                              void* d_out, int out_size, void* d_ws, size_t ws_size,
                              hipStream_t stream) {
    const float* x      = (const float*)d_in[0];
    const int*   sid    = (const int*)d_in[1];
    const int*   labels = (const int*)d_in[2];
    float* out = (float*)d_out;
    char*  ws  = (char*)d_ws;

    float*    h      = (float*)(ws + H_OFF);
    int*      perm   = (int*)(ws + PERM_OFF);
    unsigned* counts = (unsigned*)(ws + COUNTS_OFF);
    unsigned* pos    = (unsigned*)(ws + POS_OFF);
    int*      ordl   = (int*)(ws + ORDL_OFF);
    float*    E      = (float*)(ws + E_OFF);

    k_prep  <<<B_DIM,            256, 0, stream>>>(sid, perm, counts, pos, ordl);
    k_gather<<<B_DIM * S_MAXK,   256, 0, stream>>>(x, perm, counts, h);
    k_pairsE<<<B_DIM * 31,       256, 0, stream>>>(h, ordl, pos, E);
    k_final <<<1,                256, 0, stream>>>(E, ordl, pos, labels, out);
}